// Round 3
// baseline (59.292 us; speedup 1.0000x reference)
//
#include <hip/hip_runtime.h>
#include <cstdint>
#include <cstddef>

#define MAXG 128

// ---------------- compile-time: reproduce numpy legacy RandomState(42) ----------------
namespace ct {

struct MT19937 {
  uint32_t mt[624] = {};
  int mti = 0;
  constexpr void seed(uint32_t s) {
    mt[0] = s;
    for (int i = 1; i < 624; i++)
      mt[i] = 1812433253u * (mt[i-1] ^ (mt[i-1] >> 30)) + (uint32_t)i;
    mti = 624;
  }
  constexpr uint32_t next() {
    if (mti >= 624) {
      for (int i = 0; i < 624; i++) {
        uint32_t y = (mt[i] & 0x80000000u) | (mt[(i+1) % 624] & 0x7fffffffu);
        mt[i] = mt[(i+397) % 624] ^ (y >> 1) ^ ((y & 1u) ? 2567483615u : 0u);
      }
      mti = 0;
    }
    uint32_t y = mt[mti++];
    y ^= y >> 11; y ^= (y << 7) & 2636928640u; y ^= (y << 15) & 4022730752u; y ^= y >> 18;
    return y;
  }
  constexpr double rdouble() {               // legacy rk_double: two 32-bit draws
    uint32_t a = next() >> 5, b = next() >> 6;
    return ((double)a * 67108864.0 + (double)b) / 9007199254740992.0;
  }
  constexpr uint32_t masked32(uint32_t rng, uint32_t mask) {  // legacy randint
    uint32_t v = next() & mask;
    while (v > rng) v = next() & mask;
    return v;
  }
  constexpr uint32_t interval(uint32_t mx) {  // random_interval (shuffle)
    if (!mx) return 0;
    uint32_t mask = mx;
    mask |= mask >> 1; mask |= mask >> 2; mask |= mask >> 4; mask |= mask >> 8; mask |= mask >> 16;
    uint32_t v = next() & mask;
    while (v > mx) v = next() & mask;
    return v;
  }
};

// gate code: bits[1:0] = kind (0=RX,1=RY,2=RZ,3=CNOT)
//   R:    bits[5:2] = wire bit mask (8>>wire), bits[10:6] = weight index l*8+i
//   CNOT: bits[5:2] = control bit mask,        bits[9:6]  = target bit mask
struct CG { int n = 0; int code[MAXG] = {}; };

constexpr CG build_gates_ct() {
  CG gl{};
  MT19937 rng{};
  rng.seed(42);
  for (int l = 0; l < 4; l++) {
    int i = 0;
    while (i < 8) {
      if (rng.rdouble() > 0.3) {
        int g = (int)rng.masked32(2, 3);   // randint(3)
        int w = (int)rng.masked32(3, 3);   // randint(4)
        int widx = l * 8 + i;
        if (gl.n < MAXG) gl.code[gl.n++] = g | ((8 >> w) << 2) | (widx << 6);
        i++;
      } else {
        int perm[4] = {0, 1, 2, 3};
        for (int ii = 3; ii >= 1; ii--) {
          int j = (int)rng.interval((uint32_t)ii);
          int tmp = perm[ii]; perm[ii] = perm[j]; perm[j] = tmp;
        }
        int cw = perm[0], tw = perm[1];
        if (gl.n < MAXG) gl.code[gl.n++] = 3 | ((8 >> cw) << 2) | ((8 >> tw) << 6);
      }
    }
  }
  return gl;
}

constexpr CG GL = build_gates_ct();

} // namespace ct

// ---------------- kernel 1: build U, one wave, all-register, fully unrolled ----------------
// Lane c (c = tid & 15) simulates column c of the 16x16 unitary: 16 complex amps in regs.
// Gate list is constexpr -> all array indices are compile-time -> no scratch, no LDS,
// no barriers, CNOTs are register renames.
__global__ __launch_bounds__(64) void build_u(const float* __restrict__ w,
                                              float* __restrict__ ws) {
  const int c = threadIdx.x & 15;
  float sr[16], si[16];
  #pragma unroll
  for (int k = 0; k < 16; k++) { sr[k] = (k == c) ? 1.0f : 0.0f; si[k] = 0.0f; }

  #pragma unroll
  for (int g = 0; g < ct::GL.n; g++) {
    const int code = ct::GL.code[g];
    const int kind = code & 3;
    float tr[16], ti[16];
    if (kind == 3) {                        // CNOT: pure permutation
      const int cbit = (code >> 2) & 15, tbit = (code >> 6) & 15;
      #pragma unroll
      for (int k = 0; k < 16; k++) {
        const int src = (k & cbit) ? (k ^ tbit) : k;
        tr[k] = sr[src]; ti[k] = si[src];
      }
    } else {
      const int bit  = (code >> 2) & 15;
      const int widx = (code >> 6) & 31;
      float sh, ch;
      __sincosf(0.5f * w[widx], &sh, &ch);  // widx compile-time -> scalar load
      #pragma unroll
      for (int k = 0; k < 16; k++) {
        const int p = k ^ bit;
        if (kind == 0) {                    // RX: new = c*self - i*s*partner
          tr[k] = ch * sr[k] + sh * si[p];
          ti[k] = ch * si[k] - sh * sr[p];
        } else if (kind == 1) {             // RY: [[c,-s],[s,c]]
          if (k & bit) { tr[k] = ch * sr[k] + sh * sr[p]; ti[k] = ch * si[k] + sh * si[p]; }
          else         { tr[k] = ch * sr[k] - sh * sr[p]; ti[k] = ch * si[k] - sh * si[p]; }
        } else {                            // RZ: diag(c-is, c+is)
          if (k & bit) { tr[k] = ch * sr[k] - sh * si[k]; ti[k] = ch * si[k] + sh * sr[k]; }
          else         { tr[k] = ch * sr[k] + sh * si[k]; ti[k] = ch * si[k] - sh * sr[k]; }
        }
      }
    }
    #pragma unroll
    for (int k = 0; k < 16; k++) { sr[k] = tr[k]; si[k] = ti[k]; }
  }

  if (threadIdx.x < 16) {
    float2* o = (float2*)ws;               // interleaved (re,im), float2 idx = k*16 + col
    #pragma unroll
    for (int k = 0; k < 16; k++) o[k * 16 + c] = make_float2(sr[k], si[k]);
  }
}

// ---------------- kernel 2: patches + zero-fill of the whole output ----------------
// thread = (b, jj, q), q=0..63; patches kk = q and 64+q; also writes all zeros so no
// separate memset is needed. grid: 1024 blocks x 256 thr.
__global__ __launch_bounds__(256) void qonv_main(const float* __restrict__ img,
                                                 const float* __restrict__ uws,
                                                 float* __restrict__ out) {
  __shared__ float4 U4[128];               // U4[k*8+i2] = (re_{2i2}, im_{2i2}, re_{2i2+1}, im_{2i2+1})
  int t = threadIdx.x;
  if (t < 128) U4[t] = ((const float4*)uws)[t];
  __syncthreads();

  unsigned tid = blockIdx.x * 256u + (unsigned)t;
  int q  = tid & 63;                       // lane-dense patch index
  int jj = (tid >> 6) & 127;               // patch row
  int b  = tid >> 13;                      // batch

  const float* row0 = img + (size_t)(b * 512 + 2 * jj) * 1536;
  const float* row1 = row0 + 1536;

  const float inv3 = 1.0f / 3.0f;
  float s16[2][16];
  #pragma unroll
  for (int p = 0; p < 2; p++) {
    int off = 384 * p + 6 * q;             // floats; 8B-aligned (even stride)
    float2 x0 = *(const float2*)(row0 + off);
    float2 x1 = *(const float2*)(row0 + off + 2);
    float2 x2 = *(const float2*)(row0 + off + 4);
    float2 y0 = *(const float2*)(row1 + off);
    float2 y1 = *(const float2*)(row1 + off + 2);
    float2 y2 = *(const float2*)(row1 + off + 4);
    float a0 = (x0.x + x0.y + x1.x) * inv3;   // (row0, col0)
    float a1 = (x1.y + x2.x + x2.y) * inv3;   // (row0, col1)
    float a2 = (y0.x + y0.y + y1.x) * inv3;   // (row1, col0)
    float a3 = (y1.y + y2.x + y2.y) * inv3;   // (row1, col1)
    float c0, s0, c1, s1, c2, s2, c3, s3;
    __sincosf(0.5f * a0, &s0, &c0);
    __sincosf(0.5f * a1, &s1, &c1);
    __sincosf(0.5f * a2, &s2, &c2);
    __sincosf(0.5f * a3, &s3, &c3);
    float A[4] = {c0*c1, c0*s1, s0*c1, s0*s1};
    float B[4] = {c2*c3, c2*s3, s2*c3, s2*s3};
    #pragma unroll
    for (int hi = 0; hi < 4; hi++)
      #pragma unroll
      for (int lo = 0; lo < 4; lo++)
        s16[p][hi * 4 + lo] = A[hi] * B[lo];
  }

  float acc[2][4];
  #pragma unroll
  for (int p = 0; p < 2; p++)
    #pragma unroll
    for (int c = 0; c < 4; c++) acc[p][c] = 0.0f;

  #pragma unroll
  for (int k = 0; k < 16; k++) {
    float ar[2] = {0, 0}, ai[2] = {0, 0};
    #pragma unroll
    for (int i2 = 0; i2 < 8; i2++) {
      float4 u = U4[k * 8 + i2];
      #pragma unroll
      for (int p = 0; p < 2; p++) {
        ar[p] += u.x * s16[p][2*i2] + u.z * s16[p][2*i2+1];
        ai[p] += u.y * s16[p][2*i2] + u.w * s16[p][2*i2+1];
      }
    }
    #pragma unroll
    for (int p = 0; p < 2; p++) {
      float pk = ar[p]*ar[p] + ai[p]*ai[p];
      #pragma unroll
      for (int ch = 0; ch < 4; ch++) {
        if (k & (8 >> ch)) acc[p][ch] -= pk; else acc[p][ch] += pk;
      }
    }
  }

  float4* o = (float4*)out;                // one float4 = 4 channels of one (b,r,c)
  size_t rowA = ((size_t)b * 256 + jj) * 256;          // computed row
  size_t rowB = ((size_t)b * 256 + 128 + jj) * 256;    // mirrored zero row
  const float4 z4 = make_float4(0.f, 0.f, 0.f, 0.f);
  o[rowA + q]       = make_float4(acc[0][0], acc[0][1], acc[0][2], acc[0][3]);
  o[rowA + 64 + q]  = make_float4(acc[1][0], acc[1][1], acc[1][2], acc[1][3]);
  o[rowA + 128 + q] = z4;
  o[rowA + 192 + q] = z4;
  o[rowB + q]       = z4;
  o[rowB + 64 + q]  = z4;
  o[rowB + 128 + q] = z4;
  o[rowB + 192 + q] = z4;
}

extern "C" void kernel_launch(void* const* d_in, const int* in_sizes, int n_in,
                              void* d_out, int out_size, void* d_ws, size_t ws_size,
                              hipStream_t stream) {
  const float* img = (const float*)d_in[0];
  const float* wts = (const float*)d_in[1];
  float* out = (float*)d_out;

  build_u<<<1, 64, 0, stream>>>(wts, (float*)d_ws);
  qonv_main<<<1024, 256, 0, stream>>>(img, (const float*)d_ws, out);
}

// Round 4
// 25.802 us; speedup vs baseline: 2.2979x; 2.2979x over previous
//
#include <hip/hip_runtime.h>
#include <cstdint>
#include <cstddef>

#define MAXG 128

// ---------------- compile-time: reproduce numpy legacy RandomState(42) ----------------
namespace ct {

struct MT19937 {
  uint32_t mt[624] = {};
  int mti = 0;
  constexpr void seed(uint32_t s) {
    mt[0] = s;
    for (int i = 1; i < 624; i++)
      mt[i] = 1812433253u * (mt[i-1] ^ (mt[i-1] >> 30)) + (uint32_t)i;
    mti = 624;
  }
  constexpr uint32_t next() {
    if (mti >= 624) {
      for (int i = 0; i < 624; i++) {
        uint32_t y = (mt[i] & 0x80000000u) | (mt[(i+1) % 624] & 0x7fffffffu);
        mt[i] = mt[(i+397) % 624] ^ (y >> 1) ^ ((y & 1u) ? 2567483615u : 0u);
      }
      mti = 0;
    }
    uint32_t y = mt[mti++];
    y ^= y >> 11; y ^= (y << 7) & 2636928640u; y ^= (y << 15) & 4022730752u; y ^= y >> 18;
    return y;
  }
  constexpr double rdouble() {               // legacy rk_double: two 32-bit draws
    uint32_t a = next() >> 5, b = next() >> 6;
    return ((double)a * 67108864.0 + (double)b) / 9007199254740992.0;
  }
  constexpr uint32_t masked32(uint32_t rng, uint32_t mask) {  // legacy randint
    uint32_t v = next() & mask;
    while (v > rng) v = next() & mask;
    return v;
  }
  constexpr uint32_t interval(uint32_t mx) {  // random_interval (shuffle)
    if (!mx) return 0;
    uint32_t mask = mx;
    mask |= mask >> 1; mask |= mask >> 2; mask |= mask >> 4; mask |= mask >> 8; mask |= mask >> 16;
    uint32_t v = next() & mask;
    while (v > mx) v = next() & mask;
    return v;
  }
};

// gate code: bits[1:0] = kind (0=RX,1=RY,2=RZ,3=CNOT)
//   R:    bits[5:2] = wire bit mask (8>>wire), bits[10:6] = weight index l*8+i
//   CNOT: bits[5:2] = control bit mask,        bits[9:6]  = target bit mask
struct CG { int n = 0; int code[MAXG] = {}; };

constexpr CG build_gates_ct() {
  CG gl{};
  MT19937 rng{};
  rng.seed(42);
  for (int l = 0; l < 4; l++) {
    int i = 0;
    while (i < 8) {
      if (rng.rdouble() > 0.3) {
        int g = (int)rng.masked32(2, 3);   // randint(3)
        int w = (int)rng.masked32(3, 3);   // randint(4)
        int widx = l * 8 + i;
        if (gl.n < MAXG) gl.code[gl.n++] = g | ((8 >> w) << 2) | (widx << 6);
        i++;
      } else {
        int perm[4] = {0, 1, 2, 3};
        for (int ii = 3; ii >= 1; ii--) {
          int j = (int)rng.interval((uint32_t)ii);
          int tmp = perm[ii]; perm[ii] = perm[j]; perm[j] = tmp;
        }
        int cw = perm[0], tw = perm[1];
        if (gl.n < MAXG) gl.code[gl.n++] = 3 | ((8 >> cw) << 2) | ((8 >> tw) << 6);
      }
    }
  }
  return gl;
}

constexpr CG GL = build_gates_ct();

} // namespace ct

// ---------------- gate chain: template recursion => static indexing GUARANTEED ------
// Each instantiation has its gate code as a constexpr; all array subscripts and all
// kind/bit branches fold at compile time. No scratch possible (rule #20 safe).
template <int G>
__device__ __forceinline__ void apply_gates(float (&sr)[16], float (&si)[16],
                                            const float* __restrict__ w) {
  if constexpr (G < ct::GL.n) {
    constexpr int code = ct::GL.code[G];
    constexpr int kind = code & 3;
    if constexpr (kind == 3) {              // CNOT: pure register permutation
      constexpr int cbit = (code >> 2) & 15, tbit = (code >> 6) & 15;
      float tr[16], ti[16];
      #pragma unroll
      for (int k = 0; k < 16; k++) {
        const int src = (k & cbit) ? (k ^ tbit) : k;   // k, cbit, tbit all ct-const
        tr[k] = sr[src]; ti[k] = si[src];
      }
      #pragma unroll
      for (int k = 0; k < 16; k++) { sr[k] = tr[k]; si[k] = ti[k]; }
    } else {
      constexpr int bit  = (code >> 2) & 15;
      constexpr int widx = (code >> 6) & 31;
      float sh, ch;
      __sincosf(0.5f * w[widx], &sh, &ch);
      float tr[16], ti[16];
      #pragma unroll
      for (int k = 0; k < 16; k++) {
        const int p = k ^ bit;
        if constexpr (kind == 0) {          // RX: new = c*self - i*s*partner
          tr[k] = ch * sr[k] + sh * si[p];
          ti[k] = ch * si[k] - sh * sr[p];
        } else if constexpr (kind == 1) {   // RY: [[c,-s],[s,c]]
          if (k & bit) { tr[k] = ch * sr[k] + sh * sr[p]; ti[k] = ch * si[k] + sh * si[p]; }
          else         { tr[k] = ch * sr[k] - sh * sr[p]; ti[k] = ch * si[k] - sh * si[p]; }
        } else {                            // RZ: diag(c-is, c+is)
          if (k & bit) { tr[k] = ch * sr[k] - sh * si[k]; ti[k] = ch * si[k] + sh * sr[k]; }
          else         { tr[k] = ch * sr[k] + sh * si[k]; ti[k] = ch * si[k] - sh * sr[k]; }
        }
      }
      #pragma unroll
      for (int k = 0; k < 16; k++) { sr[k] = tr[k]; si[k] = ti[k]; }
    }
    apply_gates<G + 1>(sr, si, w);
  }
}

// ---------------- kernel 1: build U, one wave, all-register ----------------
// Lane c (c = tid & 15) holds column c of the 16x16 unitary: 16 complex amps in regs.
__global__ __launch_bounds__(64) void build_u(const float* __restrict__ w,
                                              float* __restrict__ ws) {
  const int c = threadIdx.x & 15;
  float sr[16], si[16];
  #pragma unroll
  for (int k = 0; k < 16; k++) { sr[k] = (k == c) ? 1.0f : 0.0f; si[k] = 0.0f; }

  apply_gates<0>(sr, si, w);

  if (threadIdx.x < 16) {
    float2* o = (float2*)ws;               // interleaved (re,im), float2 idx = k*16 + col
    #pragma unroll
    for (int k = 0; k < 16; k++) o[k * 16 + c] = make_float2(sr[k], si[k]);
  }
}

// ---------------- kernel 2: patches + zero-fill of the whole output ----------------
// thread = (b, jj, q), q=0..63; patches kk = q and 64+q; also writes all zeros so no
// separate memset is needed. grid: 1024 blocks x 256 thr.
__global__ __launch_bounds__(256) void qonv_main(const float* __restrict__ img,
                                                 const float* __restrict__ uws,
                                                 float* __restrict__ out) {
  __shared__ float4 U4[128];               // U4[k*8+i2] = (re_{2i2}, im_{2i2}, re_{2i2+1}, im_{2i2+1})
  int t = threadIdx.x;
  if (t < 128) U4[t] = ((const float4*)uws)[t];
  __syncthreads();

  unsigned tid = blockIdx.x * 256u + (unsigned)t;
  int q  = tid & 63;                       // lane-dense patch index
  int jj = (tid >> 6) & 127;               // patch row
  int b  = tid >> 13;                      // batch

  const float* row0 = img + (size_t)(b * 512 + 2 * jj) * 1536;
  const float* row1 = row0 + 1536;

  const float inv3 = 1.0f / 3.0f;
  float s16[2][16];
  #pragma unroll
  for (int p = 0; p < 2; p++) {
    int off = 384 * p + 6 * q;             // floats; 8B-aligned (even stride)
    float2 x0 = *(const float2*)(row0 + off);
    float2 x1 = *(const float2*)(row0 + off + 2);
    float2 x2 = *(const float2*)(row0 + off + 4);
    float2 y0 = *(const float2*)(row1 + off);
    float2 y1 = *(const float2*)(row1 + off + 2);
    float2 y2 = *(const float2*)(row1 + off + 4);
    float a0 = (x0.x + x0.y + x1.x) * inv3;   // (row0, col0)
    float a1 = (x1.y + x2.x + x2.y) * inv3;   // (row0, col1)
    float a2 = (y0.x + y0.y + y1.x) * inv3;   // (row1, col0)
    float a3 = (y1.y + y2.x + y2.y) * inv3;   // (row1, col1)
    float c0, s0, c1, s1, c2, s2, c3, s3;
    __sincosf(0.5f * a0, &s0, &c0);
    __sincosf(0.5f * a1, &s1, &c1);
    __sincosf(0.5f * a2, &s2, &c2);
    __sincosf(0.5f * a3, &s3, &c3);
    float A[4] = {c0*c1, c0*s1, s0*c1, s0*s1};
    float B[4] = {c2*c3, c2*s3, s2*c3, s2*s3};
    #pragma unroll
    for (int hi = 0; hi < 4; hi++)
      #pragma unroll
      for (int lo = 0; lo < 4; lo++)
        s16[p][hi * 4 + lo] = A[hi] * B[lo];
  }

  float acc[2][4];
  #pragma unroll
  for (int p = 0; p < 2; p++)
    #pragma unroll
    for (int c = 0; c < 4; c++) acc[p][c] = 0.0f;

  #pragma unroll
  for (int k = 0; k < 16; k++) {
    float ar[2] = {0, 0}, ai[2] = {0, 0};
    #pragma unroll
    for (int i2 = 0; i2 < 8; i2++) {
      float4 u = U4[k * 8 + i2];
      #pragma unroll
      for (int p = 0; p < 2; p++) {
        ar[p] += u.x * s16[p][2*i2] + u.z * s16[p][2*i2+1];
        ai[p] += u.y * s16[p][2*i2] + u.w * s16[p][2*i2+1];
      }
    }
    #pragma unroll
    for (int p = 0; p < 2; p++) {
      float pk = ar[p]*ar[p] + ai[p]*ai[p];
      #pragma unroll
      for (int ch = 0; ch < 4; ch++) {
        if (k & (8 >> ch)) acc[p][ch] -= pk; else acc[p][ch] += pk;
      }
    }
  }

  float4* o = (float4*)out;                // one float4 = 4 channels of one (b,r,c)
  size_t rowA = ((size_t)b * 256 + jj) * 256;          // computed row
  size_t rowB = ((size_t)b * 256 + 128 + jj) * 256;    // mirrored zero row
  const float4 z4 = make_float4(0.f, 0.f, 0.f, 0.f);
  o[rowA + q]       = make_float4(acc[0][0], acc[0][1], acc[0][2], acc[0][3]);
  o[rowA + 64 + q]  = make_float4(acc[1][0], acc[1][1], acc[1][2], acc[1][3]);
  o[rowA + 128 + q] = z4;
  o[rowA + 192 + q] = z4;
  o[rowB + q]       = z4;
  o[rowB + 64 + q]  = z4;
  o[rowB + 128 + q] = z4;
  o[rowB + 192 + q] = z4;
}

extern "C" void kernel_launch(void* const* d_in, const int* in_sizes, int n_in,
                              void* d_out, int out_size, void* d_ws, size_t ws_size,
                              hipStream_t stream) {
  const float* img = (const float*)d_in[0];
  const float* wts = (const float*)d_in[1];
  float* out = (float*)d_out;

  build_u<<<1, 64, 0, stream>>>(wts, (float*)d_ws);
  qonv_main<<<1024, 256, 0, stream>>>(img, (const float*)d_ws, out);
}